// Round 5
// baseline (514.558 us; speedup 1.0000x reference)
//
#include <hip/hip_runtime.h>

#define T_DIM 4096
#define H_DIM 2048
#define I_DIM 6144

#define BM 128
#define BN 128
#define BK 64
#define DBN 256

typedef __bf16 bf16x8 __attribute__((ext_vector_type(8)));
typedef float f32x4 __attribute__((ext_vector_type(4)));

__device__ __forceinline__ unsigned short f2bf(float f) {
  unsigned u = __float_as_uint(f);
  u += 0x7FFFu + ((u >> 16) & 1u);
  return (unsigned short)(u >> 16);
}
__device__ __forceinline__ float bf2f(unsigned short h) {
  return __uint_as_float(((unsigned)h) << 16);
}

// async global->LDS, 16B per lane. LDS dest must be wave-uniform base + lane*16.
__device__ __forceinline__ void async16(const unsigned short* g, unsigned short* l) {
  __builtin_amdgcn_global_load_lds(
      (__attribute__((address_space(1))) void*)g,
      (__attribute__((address_space(3))) void*)l, 16, 0, 0);
}

// ---- weight LPBQ qdq: blocks of 32 along contiguous dim; 8 lanes = one block.
__device__ __forceinline__ void qdq_w_one(const float* __restrict__ w,
                                          unsigned short* __restrict__ out, int i) {
  float4 v = ((const float4*)w)[i];
  float m = fmaxf(fmaxf(fabsf(v.x), fabsf(v.y)), fmaxf(fabsf(v.z), fabsf(v.w)));
  m = fmaxf(m, __shfl_xor(m, 1));
  m = fmaxf(m, __shfl_xor(m, 2));
  m = fmaxf(m, __shfl_xor(m, 4));
  const float s = fmaxf(m * (1.0f / 7.0f), 1e-12f);
  const float inv = 1.0f / s;
  ushort4 o;
  o.x = f2bf(fminf(fmaxf(rintf(v.x * inv), -8.f), 7.f) * s);
  o.y = f2bf(fminf(fmaxf(rintf(v.y * inv), -8.f), 7.f) * s);
  o.z = f2bf(fminf(fmaxf(rintf(v.z * inv), -8.f), 7.f) * s);
  o.w = f2bf(fminf(fmaxf(rintf(v.w * inv), -8.f), 7.f) * s);
  ((ushort4*)out)[i] = o;
}

// prep: region 0 = cast x->bf16; regions 1,2,3 = LPBQ of w_up, w_gate, w_down.
// Region boundaries are multiples of 256 -> shuffle octets stay in one branch.
__global__ void k_prep(const float* __restrict__ x, unsigned short* __restrict__ xq,
                       const float* __restrict__ w0, unsigned short* __restrict__ o0,
                       const float* __restrict__ w1, unsigned short* __restrict__ o1,
                       const float* __restrict__ w2, unsigned short* __restrict__ o2,
                       int nx4, int nw4) {
  const int i = blockIdx.x * blockDim.x + threadIdx.x;
  if (i < nx4) {
    float4 v = ((const float4*)x)[i];
    ushort4 o;
    o.x = f2bf(v.x); o.y = f2bf(v.y); o.z = f2bf(v.z); o.w = f2bf(v.w);
    ((ushort4*)xq)[i] = o;
  } else if (i < nx4 + nw4) {
    qdq_w_one(w0, o0, i - nx4);
  } else if (i < nx4 + 2 * nw4) {
    qdq_w_one(w1, o1, i - nx4 - nw4);
  } else {
    qdq_w_one(w2, o2, i - nx4 - 2 * nw4);
  }
}

// fused up+gate (round-2 verified: 184 us, MfmaUtil 52%). 512 threads / 8
// waves: waves 0-3 compute the up 128x128 tile (one 64x64 quadrant each),
// waves 4-7 gate for the same quadrants from the same A-tile. Single-buffer
// 48 KiB -> multiple blocks/CU; inter-block overlap hides the barrier drain
// (explicit double-buffer at 96 KiB measured WORSE: 224 us, R3).
__launch_bounds__(512)
__global__ void k_gemm_ug_fused(const unsigned short* __restrict__ xq,
                                const unsigned short* __restrict__ wu,
                                const unsigned short* __restrict__ wg,
                                unsigned short* __restrict__ mid) {
  __shared__ unsigned short lds[3 * BM * BK];  // A | Bu | Bg = 48 KiB
  const int tid = threadIdx.x;
  const int lane = tid & 63;
  const int wv = tid >> 6;      // 0..7
  const int half = wv >> 2;     // 0 = up, 1 = gate
  const int wq = wv & 3;
  const int wm = (wq >> 1) << 6;
  const int wn = (wq & 1) << 6;
  const int quad = lane >> 4;
  const int l16 = lane & 15;
  const int sw = (l16 & 7);
  const long m0 = (long)blockIdx.y * BM;
  const long n0 = (long)blockIdx.x * BN;
  unsigned short* ldsB = lds + (size_t)(1 + half) * BM * BK;

  f32x4 acc[4][4] = {};

  for (int k0 = 0; k0 < H_DIM; k0 += BK) {
    __syncthreads();
    // 3072 chunks (A:0-1023, Bu:1024-2047, Bg:2048-3071), 512 threads -> 6 each.
    // Wave-aligned 64-chunk runs never cross a 1024-chunk tile boundary, so the
    // LDS dest stays wave-uniform-base + lane*16.
#pragma unroll
    for (int r = 0; r < 6; ++r) {
      const int idx = r * 512 + tid;
      const int t = idx >> 10;
      const int c = idx & 1023;
      const int row = c >> 3;
      const int colc = ((c & 7) ^ (row & 7)) * 8;
      const unsigned short* src =
          (t == 0) ? xq + (m0 + row) * H_DIM + k0 + colc
        : (t == 1) ? wu + (n0 + row) * H_DIM + k0 + colc
                   : wg + (n0 + row) * H_DIM + k0 + colc;
      async16(src, lds + (size_t)t * (BM * BK) + (size_t)c * 8);
    }
    __syncthreads();

#pragma unroll
    for (int ks = 0; ks < BK / 32; ++ks) {
      bf16x8 af[4], bfr[4];
      const int sj = ((ks * 4 + quad) ^ sw) * 8;
#pragma unroll
      for (int i = 0; i < 4; ++i) {
        af[i] = *(const bf16x8*)(lds + (wm + i * 16 + l16) * BK + sj);
        bfr[i] = *(const bf16x8*)(ldsB + (wn + i * 16 + l16) * BK + sj);
      }
#pragma unroll
      for (int i = 0; i < 4; ++i)
#pragma unroll
        for (int j = 0; j < 4; ++j)
          acc[i][j] = __builtin_amdgcn_mfma_f32_16x16x32_bf16(af[i], bfr[j], acc[i][j], 0, 0, 0);
    }
  }

  // ---- epilogue: exchange gate tile via LDS (128x128 bf16 = 32 KiB, fits).
  // Column-group XOR by (row>>2)&3 spreads the 4 quads' rows over all 32 banks.
  __syncthreads();
  const int rbase = wm + (quad << 2);
  const int cbase = wn + l16;
  if (half) {
#pragma unroll
    for (int i = 0; i < 4; ++i)
#pragma unroll
      for (int r = 0; r < 4; ++r) {
        const int row = rbase + i * 16 + r;
        const int swz = ((row >> 2) & 3) << 4;
#pragma unroll
        for (int j = 0; j < 4; ++j) {
          const int col = cbase + j * 16;
          lds[row * 128 + (col ^ swz)] = f2bf(acc[i][j][r]);
        }
      }
  }
  __syncthreads();
  if (!half) {
#pragma unroll
    for (int i = 0; i < 4; ++i)
#pragma unroll
      for (int r = 0; r < 4; ++r) {
        const int row = rbase + i * 16 + r;
        const int swz = ((row >> 2) & 3) << 4;
        const long grow = m0 + row;
#pragma unroll
        for (int j = 0; j < 4; ++j) {
          const int col = cbase + j * 16;
          const float u = acc[i][j][r];
          const float g = bf2f(lds[row * 128 + (col ^ swz)]);
          const float a = u * __frcp_rn(1.0f + __expf(-u));
          mid[grow * (long)I_DIM + n0 + col] = f2bf(a * g);
        }
      }
  }
}

// down GEMM: 8-wave 128x256 tile (staging ratio 0.1875 KiB/MFMA = fused ug),
// SINGLE-buffer 48 KiB, 2-barrier structure -> 2 blocks/CU co-resident hide
// the barrier drain (R3's 96 KiB double-buffer variant was occupancy-capped).
// Grid (8,32) = 256 blocks, exactly 1 wavefront of blocks, no tail.
__launch_bounds__(512)
__global__ void k_gemm_down(const unsigned short* __restrict__ A,
                            const unsigned short* __restrict__ B,
                            float* __restrict__ C) {
  __shared__ unsigned short lds[(BM + DBN) * BK];  // 48 KiB
  const int tid = threadIdx.x;
  const int lane = tid & 63;
  const int wv = tid >> 6;
  const int wm = (wv >> 2) << 6;   // 2 row-halves of 128
  const int wn = (wv & 3) << 6;    // 4 col-quadrants of 256
  const int quad = lane >> 4;
  const int l16 = lane & 15;
  const int sw = (l16 & 7);
  const long m0 = (long)blockIdx.y * BM;
  const long n0 = (long)blockIdx.x * DBN;
  unsigned short* ldsB = lds + BM * BK;

  f32x4 acc[4][4] = {};

  for (int k0 = 0; k0 < I_DIM; k0 += BK) {
    __syncthreads();
    // A: chunks 0-1023 (128 rows), B: chunks 1024-3071 (256 rows); 6/thread.
    // Wave runs of 64 chunks never cross the 1024-chunk region boundary.
#pragma unroll
    for (int r = 0; r < 6; ++r) {
      const int idx = r * 512 + tid;
      if (idx < 1024) {
        const int row = idx >> 3;
        const int colc = ((idx & 7) ^ (row & 7)) * 8;
        async16(A + (m0 + row) * I_DIM + k0 + colc, lds + (size_t)idx * 8);
      } else {
        const int c = idx - 1024;
        const int row = c >> 3;
        const int colc = ((c & 7) ^ (row & 7)) * 8;
        async16(B + (n0 + row) * I_DIM + k0 + colc, ldsB + (size_t)c * 8);
      }
    }
    __syncthreads();

#pragma unroll
    for (int ks = 0; ks < BK / 32; ++ks) {
      bf16x8 af[4], bfr[4];
      const int sj = ((ks * 4 + quad) ^ sw) * 8;
#pragma unroll
      for (int i = 0; i < 4; ++i) {
        af[i] = *(const bf16x8*)(lds + (wm + i * 16 + l16) * BK + sj);
        bfr[i] = *(const bf16x8*)(ldsB + (wn + i * 16 + l16) * BK + sj);
      }
#pragma unroll
      for (int i = 0; i < 4; ++i)
#pragma unroll
        for (int j = 0; j < 4; ++j)
          acc[i][j] = __builtin_amdgcn_mfma_f32_16x16x32_bf16(af[i], bfr[j], acc[i][j], 0, 0, 0);
    }
  }

  const long rbase = m0 + wm + (quad << 2);
  const long cbase = n0 + wn + l16;
#pragma unroll
  for (int i = 0; i < 4; ++i)
#pragma unroll
    for (int r = 0; r < 4; ++r) {
      const long grow = rbase + i * 16 + r;
#pragma unroll
      for (int j = 0; j < 4; ++j)
        C[grow * (long)H_DIM + cbase + j * 16] = acc[i][j][r];
    }
}

extern "C" void kernel_launch(void* const* d_in, const int* in_sizes, int n_in,
                              void* d_out, int out_size, void* d_ws, size_t ws_size,
                              hipStream_t stream) {
  (void)in_sizes; (void)n_in; (void)out_size; (void)ws_size;
  const float* x      = (const float*)d_in[0];
  const float* w_gate = (const float*)d_in[1];
  const float* w_up   = (const float*)d_in[2];
  const float* w_down = (const float*)d_in[3];

  char* ws = (char*)d_ws;
  const size_t OFF_XQ = 0;
  const size_t OFF_WU = OFF_XQ + (size_t)T_DIM * H_DIM * 2;   // xq  16.8 MB
  const size_t OFF_WD = OFF_WU + (size_t)I_DIM * H_DIM * 2;   // wuq 25.2 MB
  const size_t OFF_MID = OFF_WD + (size_t)I_DIM * H_DIM * 2;  // wdq 25.2 MB
  unsigned short* xq  = (unsigned short*)(ws + OFF_XQ);
  unsigned short* wuq = (unsigned short*)(ws + OFF_WU);
  unsigned short* wdq = (unsigned short*)(ws + OFF_WD);
  unsigned short* mid = (unsigned short*)(ws + OFF_MID);      // mid 50.3 MB
  unsigned short* wgq = (unsigned short*)d_out;               // gate weights staged in d_out
                                                              // (dead before down GEMM writes)

  const int nx4 = T_DIM * H_DIM / 4;   // 2097152 (multiple of 256)
  const int nw4 = I_DIM * H_DIM / 4;   // 3145728 (multiple of 256)

  // x-cast + w_up/w_gate/w_down LPBQ in one dispatch (block-aligned regions)
  k_prep<<<(nx4 + 3 * nw4) / 256, 256, 0, stream>>>(x, xq, w_up, wuq, w_gate, wgq,
                                                    w_down, wdq, nx4, nw4);

  // fused up+gate GEMM + silu*mul: 48x32 = 1536 blocks of 512 threads -> mid
  k_gemm_ug_fused<<<dim3(I_DIM / BN, T_DIM / BM), 512, 0, stream>>>(xq, wuq, wgq, mid);

  // out = mid @ w_down^T, fp32: 8x32 = 256 blocks of 512 threads
  k_gemm_down<<<dim3(H_DIM / DBN, T_DIM / BM), 512, 0, stream>>>(mid, wdq, (float*)d_out);
}

// Round 6
// 477.455 us; speedup vs baseline: 1.0777x; 1.0777x over previous
//
#include <hip/hip_runtime.h>

#define T_DIM 4096
#define H_DIM 2048
#define I_DIM 6144

#define BM 128
#define BN 128
#define BK 64
#define DBN 256

typedef __bf16 bf16x8 __attribute__((ext_vector_type(8)));
typedef float f32x4 __attribute__((ext_vector_type(4)));

__device__ __forceinline__ unsigned short f2bf(float f) {
  unsigned u = __float_as_uint(f);
  u += 0x7FFFu + ((u >> 16) & 1u);
  return (unsigned short)(u >> 16);
}
__device__ __forceinline__ float bf2f(unsigned short h) {
  return __uint_as_float(((unsigned)h) << 16);
}

// async global->LDS, 16B per lane. LDS dest must be wave-uniform base + lane*16.
__device__ __forceinline__ void async16(const unsigned short* g, unsigned short* l) {
  __builtin_amdgcn_global_load_lds(
      (__attribute__((address_space(1))) void*)g,
      (__attribute__((address_space(3))) void*)l, 16, 0, 0);
}

// ---- weight LPBQ qdq: blocks of 32 along contiguous dim; 8 lanes = one block.
__device__ __forceinline__ void qdq_w_one(const float* __restrict__ w,
                                          unsigned short* __restrict__ out, int i) {
  float4 v = ((const float4*)w)[i];
  float m = fmaxf(fmaxf(fabsf(v.x), fabsf(v.y)), fmaxf(fabsf(v.z), fabsf(v.w)));
  m = fmaxf(m, __shfl_xor(m, 1));
  m = fmaxf(m, __shfl_xor(m, 2));
  m = fmaxf(m, __shfl_xor(m, 4));
  const float s = fmaxf(m * (1.0f / 7.0f), 1e-12f);
  const float inv = 1.0f / s;
  ushort4 o;
  o.x = f2bf(fminf(fmaxf(rintf(v.x * inv), -8.f), 7.f) * s);
  o.y = f2bf(fminf(fmaxf(rintf(v.y * inv), -8.f), 7.f) * s);
  o.z = f2bf(fminf(fmaxf(rintf(v.z * inv), -8.f), 7.f) * s);
  o.w = f2bf(fminf(fmaxf(rintf(v.w * inv), -8.f), 7.f) * s);
  ((ushort4*)out)[i] = o;
}

// prep: region 0 = cast x->bf16; regions 1,2,3 = LPBQ of w_up, w_gate, w_down.
// Region boundaries are multiples of 256 -> shuffle octets stay in one branch.
__global__ void k_prep(const float* __restrict__ x, unsigned short* __restrict__ xq,
                       const float* __restrict__ w0, unsigned short* __restrict__ o0,
                       const float* __restrict__ w1, unsigned short* __restrict__ o1,
                       const float* __restrict__ w2, unsigned short* __restrict__ o2,
                       int nx4, int nw4) {
  const int i = blockIdx.x * blockDim.x + threadIdx.x;
  if (i < nx4) {
    float4 v = ((const float4*)x)[i];
    ushort4 o;
    o.x = f2bf(v.x); o.y = f2bf(v.y); o.z = f2bf(v.z); o.w = f2bf(v.w);
    ((ushort4*)xq)[i] = o;
  } else if (i < nx4 + nw4) {
    qdq_w_one(w0, o0, i - nx4);
  } else if (i < nx4 + 2 * nw4) {
    qdq_w_one(w1, o1, i - nx4 - nw4);
  } else {
    qdq_w_one(w2, o2, i - nx4 - 2 * nw4);
  }
}

// fused up+gate (R2 verified: 184-205 us, MfmaUtil 47-52%). 512 threads / 8
// waves: waves 0-3 compute the up 128x128 tile (one 64x64 quadrant each),
// waves 4-7 gate for the same quadrants from the same A-tile. Single-buffer
// 48 KiB -> multiple blocks/CU; inter-block overlap hides the barrier drain
// (explicit double-buffer at 96 KiB measured WORSE: 224 us, R3). FROZEN.
__launch_bounds__(512)
__global__ void k_gemm_ug_fused(const unsigned short* __restrict__ xq,
                                const unsigned short* __restrict__ wu,
                                const unsigned short* __restrict__ wg,
                                unsigned short* __restrict__ mid) {
  __shared__ unsigned short lds[3 * BM * BK];  // A | Bu | Bg = 48 KiB
  const int tid = threadIdx.x;
  const int lane = tid & 63;
  const int wv = tid >> 6;      // 0..7
  const int half = wv >> 2;     // 0 = up, 1 = gate
  const int wq = wv & 3;
  const int wm = (wq >> 1) << 6;
  const int wn = (wq & 1) << 6;
  const int quad = lane >> 4;
  const int l16 = lane & 15;
  const int sw = (l16 & 7);
  const long m0 = (long)blockIdx.y * BM;
  const long n0 = (long)blockIdx.x * BN;
  unsigned short* ldsB = lds + (size_t)(1 + half) * BM * BK;

  f32x4 acc[4][4] = {};

  for (int k0 = 0; k0 < H_DIM; k0 += BK) {
    __syncthreads();
    // 3072 chunks (A:0-1023, Bu:1024-2047, Bg:2048-3071), 512 threads -> 6 each.
    // Wave-aligned 64-chunk runs never cross a 1024-chunk tile boundary, so the
    // LDS dest stays wave-uniform-base + lane*16.
#pragma unroll
    for (int r = 0; r < 6; ++r) {
      const int idx = r * 512 + tid;
      const int t = idx >> 10;
      const int c = idx & 1023;
      const int row = c >> 3;
      const int colc = ((c & 7) ^ (row & 7)) * 8;
      const unsigned short* src =
          (t == 0) ? xq + (m0 + row) * H_DIM + k0 + colc
        : (t == 1) ? wu + (n0 + row) * H_DIM + k0 + colc
                   : wg + (n0 + row) * H_DIM + k0 + colc;
      async16(src, lds + (size_t)t * (BM * BK) + (size_t)c * 8);
    }
    __syncthreads();

#pragma unroll
    for (int ks = 0; ks < BK / 32; ++ks) {
      bf16x8 af[4], bfr[4];
      const int sj = ((ks * 4 + quad) ^ sw) * 8;
#pragma unroll
      for (int i = 0; i < 4; ++i) {
        af[i] = *(const bf16x8*)(lds + (wm + i * 16 + l16) * BK + sj);
        bfr[i] = *(const bf16x8*)(ldsB + (wn + i * 16 + l16) * BK + sj);
      }
#pragma unroll
      for (int i = 0; i < 4; ++i)
#pragma unroll
        for (int j = 0; j < 4; ++j)
          acc[i][j] = __builtin_amdgcn_mfma_f32_16x16x32_bf16(af[i], bfr[j], acc[i][j], 0, 0, 0);
    }
  }

  // ---- epilogue: exchange gate tile via LDS (128x128 bf16 = 32 KiB, fits).
  // Column-group XOR by (row>>2)&3 spreads the 4 quads' rows over all 32 banks.
  __syncthreads();
  const int rbase = wm + (quad << 2);
  const int cbase = wn + l16;
  if (half) {
#pragma unroll
    for (int i = 0; i < 4; ++i)
#pragma unroll
      for (int r = 0; r < 4; ++r) {
        const int row = rbase + i * 16 + r;
        const int swz = ((row >> 2) & 3) << 4;
#pragma unroll
        for (int j = 0; j < 4; ++j) {
          const int col = cbase + j * 16;
          lds[row * 128 + (col ^ swz)] = f2bf(acc[i][j][r]);
        }
      }
  }
  __syncthreads();
  if (!half) {
#pragma unroll
    for (int i = 0; i < 4; ++i)
#pragma unroll
      for (int r = 0; r < 4; ++r) {
        const int row = rbase + i * 16 + r;
        const int swz = ((row >> 2) & 3) << 4;
        const long grow = m0 + row;
#pragma unroll
        for (int j = 0; j < 4; ++j) {
          const int col = cbase + j * 16;
          const float u = acc[i][j][r];
          const float g = bf2f(lds[row * 128 + (col ^ swz)]);
          const float a = u * __frcp_rn(1.0f + __expf(-u));
          mid[grow * (long)I_DIM + n0 + col] = f2bf(a * g);
        }
      }
  }
}

// down GEMM, split-K=2: 8-wave 128x256 tile (staging ratio 0.1875 KiB/MFMA =
// fused ug), single-buffer 48 KiB, 2-phase. Grid (8,32,2) = 512 blocks =
// 2 blocks/CU (R5 lesson: the 256-block version was 1 block/CU -> barrier
// drain fully exposed, ~2x slower per step). z=0 -> C0 (d_out), z=1 -> C1
// (partial in dead xq/wuq workspace); k_add folds them.
__launch_bounds__(512)
__global__ void k_gemm_down(const unsigned short* __restrict__ A,
                            const unsigned short* __restrict__ B,
                            float* __restrict__ C0, float* __restrict__ C1) {
  __shared__ unsigned short lds[(BM + DBN) * BK];  // 48 KiB
  const int tid = threadIdx.x;
  const int lane = tid & 63;
  const int wv = tid >> 6;
  const int wm = (wv >> 2) << 6;   // 2 row-halves of 128
  const int wn = (wv & 3) << 6;    // 4 col-quadrants of 256
  const int quad = lane >> 4;
  const int l16 = lane & 15;
  const int sw = (l16 & 7);
  const long m0 = (long)blockIdx.y * BM;
  const long n0 = (long)blockIdx.x * DBN;
  const int kbase = (int)blockIdx.z * (I_DIM / 2);
  float* __restrict__ C = blockIdx.z ? C1 : C0;
  unsigned short* ldsB = lds + BM * BK;

  f32x4 acc[4][4] = {};

  for (int k0 = kbase; k0 < kbase + I_DIM / 2; k0 += BK) {
    __syncthreads();
    // A: chunks 0-1023 (128 rows), B: chunks 1024-3071 (256 rows); 6/thread.
    // Wave runs of 64 chunks never cross the 1024-chunk region boundary.
#pragma unroll
    for (int r = 0; r < 6; ++r) {
      const int idx = r * 512 + tid;
      if (idx < 1024) {
        const int row = idx >> 3;
        const int colc = ((idx & 7) ^ (row & 7)) * 8;
        async16(A + (m0 + row) * I_DIM + k0 + colc, lds + (size_t)idx * 8);
      } else {
        const int c = idx - 1024;
        const int row = c >> 3;
        const int colc = ((c & 7) ^ (row & 7)) * 8;
        async16(B + (n0 + row) * I_DIM + k0 + colc, ldsB + (size_t)c * 8);
      }
    }
    __syncthreads();

#pragma unroll
    for (int ks = 0; ks < BK / 32; ++ks) {
      bf16x8 af[4], bfr[4];
      const int sj = ((ks * 4 + quad) ^ sw) * 8;
#pragma unroll
      for (int i = 0; i < 4; ++i) {
        af[i] = *(const bf16x8*)(lds + (wm + i * 16 + l16) * BK + sj);
        bfr[i] = *(const bf16x8*)(ldsB + (wn + i * 16 + l16) * BK + sj);
      }
#pragma unroll
      for (int i = 0; i < 4; ++i)
#pragma unroll
        for (int j = 0; j < 4; ++j)
          acc[i][j] = __builtin_amdgcn_mfma_f32_16x16x32_bf16(af[i], bfr[j], acc[i][j], 0, 0, 0);
    }
  }

  const long rbase = m0 + wm + (quad << 2);
  const long cbase = n0 + wn + l16;
#pragma unroll
  for (int i = 0; i < 4; ++i)
#pragma unroll
    for (int r = 0; r < 4; ++r) {
      const long grow = rbase + i * 16 + r;
#pragma unroll
      for (int j = 0; j < 4; ++j)
        C[grow * (long)H_DIM + cbase + j * 16] = acc[i][j][r];
    }
}

// out += partial (fp32, float4-vectorized). 100 MB traffic ~ 17 us.
__global__ void k_add(float* __restrict__ out, const float* __restrict__ p, int n4) {
  const int i = blockIdx.x * blockDim.x + threadIdx.x;
  if (i >= n4) return;
  float4 a = ((const float4*)out)[i];
  const float4 b = ((const float4*)p)[i];
  a.x += b.x; a.y += b.y; a.z += b.z; a.w += b.w;
  ((float4*)out)[i] = a;
}

extern "C" void kernel_launch(void* const* d_in, const int* in_sizes, int n_in,
                              void* d_out, int out_size, void* d_ws, size_t ws_size,
                              hipStream_t stream) {
  (void)in_sizes; (void)n_in; (void)out_size; (void)ws_size;
  const float* x      = (const float*)d_in[0];
  const float* w_gate = (const float*)d_in[1];
  const float* w_up   = (const float*)d_in[2];
  const float* w_down = (const float*)d_in[3];

  char* ws = (char*)d_ws;
  const size_t OFF_XQ = 0;
  const size_t OFF_WU = OFF_XQ + (size_t)T_DIM * H_DIM * 2;   // xq  16.8 MB
  const size_t OFF_WD = OFF_WU + (size_t)I_DIM * H_DIM * 2;   // wuq 25.2 MB
  const size_t OFF_MID = OFF_WD + (size_t)I_DIM * H_DIM * 2;  // wdq 25.2 MB
  unsigned short* xq  = (unsigned short*)(ws + OFF_XQ);
  unsigned short* wuq = (unsigned short*)(ws + OFF_WU);
  unsigned short* wdq = (unsigned short*)(ws + OFF_WD);
  unsigned short* mid = (unsigned short*)(ws + OFF_MID);      // mid 50.3 MB
  unsigned short* wgq = (unsigned short*)d_out;               // gate weights staged in d_out
                                                              // (dead before down GEMM writes)
  // split-K partial: overlays xq+wuq (both dead after ug). 33.5 MB < 42 MB.
  float* part1 = (float*)(ws + OFF_XQ);

  const int nx4 = T_DIM * H_DIM / 4;   // 2097152 (multiple of 256)
  const int nw4 = I_DIM * H_DIM / 4;   // 3145728 (multiple of 256)
  const int no4 = T_DIM * H_DIM / 4;   // output float4 count

  // x-cast + w_up/w_gate/w_down LPBQ in one dispatch (block-aligned regions)
  k_prep<<<(nx4 + 3 * nw4) / 256, 256, 0, stream>>>(x, xq, w_up, wuq, w_gate, wgq,
                                                    w_down, wdq, nx4, nw4);

  // fused up+gate GEMM + silu*mul: 48x32 = 1536 blocks of 512 threads -> mid
  k_gemm_ug_fused<<<dim3(I_DIM / BN, T_DIM / BM), 512, 0, stream>>>(xq, wuq, wgq, mid);

  // out = mid @ w_down^T, fp32, split-K=2: (8,32,2) = 512 blocks of 512 threads
  k_gemm_down<<<dim3(H_DIM / DBN, T_DIM / BM, 2), 512, 0, stream>>>(mid, wdq,
                                                                    (float*)d_out, part1);

  // out += partial
  k_add<<<no4 / 256, 256, 0, stream>>>((float*)d_out, part1, no4);
}